// Round 4
// baseline (311.323 us; speedup 1.0000x reference)
//
#include <hip/hip_runtime.h>
#include <cstdint>
#include <cstddef>

#define Nn 2048
#define FIN 256
#define EFEAT 32
#define HID 64
#define NH 4
#define NL 3
#define LRELU_A 0.2f

typedef _Float16 h4 __attribute__((ext_vector_type(4)));
typedef _Float16 h8 __attribute__((ext_vector_type(8)));
typedef float f4 __attribute__((ext_vector_type(4)));

#define NEGH ((_Float16)(-60000.0f))

// ---------------- coef[l,h,f] = sum_i W_e[l,h,f,i] * (sum_o W[l,h,i,o]*a3[l,h,o]) ----------------
__global__ void k_coef(const float* __restrict__ W, const float* __restrict__ We,
                       const float* __restrict__ a, float* __restrict__ coef) {
  int lh = blockIdx.x;          // 0..11  (l*4+h)
  int t = threadIdx.x;          // 256
  __shared__ float tl[FIN];
  const float* Wb = W + (size_t)lh * FIN * HID;
  const float* ab = a + (size_t)lh * (3 * HID) + 2 * HID;
  float acc = 0.f;
#pragma unroll 8
  for (int o = 0; o < HID; ++o) acc = fmaf(Wb[(size_t)t * HID + o], ab[o], acc);
  tl[t] = acc;
  __syncthreads();
  if (t < EFEAT) {
    const float* Web = We + ((size_t)lh * EFEAT + t) * FIN;
    float c = 0.f;
    for (int i = 0; i < FIN; ++i) c = fmaf(Web[i], tl[i], c);
    coef[lh * EFEAT + t] = c;
  }
}

// ---------------- e-score precompute, fp16, m-tiled layout es[c][m/64][n][m%64] ----------------
// Predicated e loads (skip masked fetch); single full-width select store per channel:
// a wave's 64 lanes (consecutive m, same n) store 128 B contiguous -> no partial-sector RMW.
template <int C>
__global__ __launch_bounds__(256) void k_escore(
    const float* __restrict__ e, const int* __restrict__ adj,
    const float* __restrict__ coef, _Float16* __restrict__ es) {
  size_t idx = (size_t)blockIdx.x * 256 + threadIdx.x;   // n*Nn + m
  int m = (int)(idx & (Nn - 1));
  int n = (int)(idx >> 11);
  int mt = m >> 6, ml = m & 63;
  const size_t cstride = (size_t)32 * Nn * 64;
  size_t sbase = ((size_t)mt * Nn + n) * 64 + (size_t)ml;
  int aj = adj[idx];
  float evv[EFEAT] = {};
  if (aj != 0) {
    const float4* ep = (const float4*)(e + idx * EFEAT);
#pragma unroll
    for (int g = 0; g < 8; ++g) {
      float4 v = ep[g];
      evv[g * 4 + 0] = v.x; evv[g * 4 + 1] = v.y; evv[g * 4 + 2] = v.z; evv[g * 4 + 3] = v.w;
    }
  }
#pragma clang loop unroll(disable)
  for (int c = 0; c < C; ++c) {
    const float* cf = coef + c * EFEAT;   // wave-uniform -> s_load
    float acc = 0.f;
#pragma unroll
    for (int f = 0; f < EFEAT; ++f) acc = fmaf(evv[f], cf[f], acc);
    es[(size_t)c * cstride + sbase] = aj ? (_Float16)acc : NEGH;
  }
}

// ---------------- h = x @ W[l]; emit hT fp16 m-tiled [h][n/64][o][n%64], s1, s2 ----------------
__global__ __launch_bounds__(256) void k_h(
    const float* __restrict__ x, const float* __restrict__ W,
    const float* __restrict__ a, int layer,
    _Float16* __restrict__ hT, float* __restrict__ s1, float* __restrict__ s2) {
  int t = threadIdx.x;
  int n0 = blockIdx.x * 8;
  int h = t >> 6, o = t & 63;
  const float* Wb = W + ((size_t)(layer * NH + h) * FIN) * HID + o;
  const float* xb = x + (size_t)n0 * FIN;
  float acc[8] = {};
  for (int i0 = 0; i0 < FIN; i0 += 4) {
    float w0 = Wb[(size_t)(i0 + 0) * HID];
    float w1 = Wb[(size_t)(i0 + 1) * HID];
    float w2 = Wb[(size_t)(i0 + 2) * HID];
    float w3 = Wb[(size_t)(i0 + 3) * HID];
#pragma unroll
    for (int j = 0; j < 8; ++j) {
      float4 xv = *(const float4*)(xb + (size_t)j * FIN + i0);   // uniform -> SGPR
      acc[j] = fmaf(xv.x, w0, acc[j]);
      acc[j] = fmaf(xv.y, w1, acc[j]);
      acc[j] = fmaf(xv.z, w2, acc[j]);
      acc[j] = fmaf(xv.w, w3, acc[j]);
    }
  }
  const float* ab = a + (size_t)(layer * NH + h) * (3 * HID);
  float a1v = ab[o], a2v = ab[HID + o];
#pragma unroll
  for (int j = 0; j < 8; ++j) {
    float r1 = acc[j] * a1v, r2 = acc[j] * a2v;
#pragma unroll
    for (int d = 1; d < 64; d <<= 1) {
      r1 += __shfl_xor(r1, d, 64);
      r2 += __shfl_xor(r2, d, 64);
    }
    if (o == 0) { s1[h * Nn + n0 + j] = r1; s2[h * Nn + n0 + j] = r2; }
  }
  int mt = n0 >> 6, ml = n0 & 63;
  h8 hv;
#pragma unroll
  for (int j = 0; j < 8; ++j) hv[j] = (_Float16)acc[j];
  *(h8*)(hT + (((size_t)h * 32 + mt) * 64 + o) * 64 + ml) = hv;
}

// ---------------- attention: h'^T = h^T @ p^T via mfma_f32_16x16x16f16, online softmax ----------------
// block = 8 waves (512 thr), one head, 16 rows. Wave w covers m in [w*256, w*256+256) -> 16 iters.
// Lane l: row n = n0 + (l&15); B-frag m-subchunk (l>>4)*4+j. Defer-max (THR=0, exact numerics).
// Epilogue fused: for non-last layers writes elu -> xnext [n][h*64+o]; last layer writes hp.
__global__ __launch_bounds__(512) void k_attn(
    const _Float16* __restrict__ es, const _Float16* __restrict__ hT,
    const float* __restrict__ s1, const float* __restrict__ s2,
    float* __restrict__ hp, float* __restrict__ xn, int layer, int last) {
  int h = blockIdx.x;
  int n0 = blockIdx.y * 16;
  int t = threadIdx.x;
  int w = t >> 6;
  int l = t & 63;
  int col = l & 15, grp = l >> 4;
  int n = n0 + col;
  float s1v = s1[h * Nn + n];
  const _Float16* esb = es + (size_t)(layer * NH + h) * ((size_t)32 * Nn * 64);
  const _Float16* hTb = hT + (size_t)h * ((size_t)32 * 64 * 64);
  const float* s2b = s2 + h * Nn;

  float M = -3.0e38f, S = 0.f;
  f4 acc[4] = {};

  for (int c16 = 0; c16 < 16; ++c16) {
    int m0 = w * 256 + c16 * 16;
    int mt = m0 >> 6;
    int ml0 = (m0 & 63) + grp * 4;
    h4 ev = *(const h4*)(esb + ((size_t)mt * Nn + n) * 64 + ml0);
    float4 sv = *(const float4*)(s2b + m0 + grp * 4);
    float sc0 = s1v + sv.x + (float)ev[0]; sc0 = fmaxf(sc0, LRELU_A * sc0);
    float sc1 = s1v + sv.y + (float)ev[1]; sc1 = fmaxf(sc1, LRELU_A * sc1);
    float sc2 = s1v + sv.z + (float)ev[2]; sc2 = fmaxf(sc2, LRELU_A * sc2);
    float sc3 = s1v + sv.w + (float)ev[3]; sc3 = fmaxf(sc3, LRELU_A * sc3);
    float cm = fmaxf(fmaxf(sc0, sc1), fmaxf(sc2, sc3));
    cm = fmaxf(cm, __shfl_xor(cm, 16, 64));   // combine 4 groups (same row set)
    cm = fmaxf(cm, __shfl_xor(cm, 32, 64));
    if (__any(cm > M)) {                      // defer-max THR=0: exact
      float Mn = fmaxf(M, cm);
      float fac = __expf(M - Mn);
      M = Mn;
      S *= fac;
#pragma unroll
      for (int ot = 0; ot < 4; ++ot) acc[ot] *= fac;
    }
    h4 pb;
    pb[0] = (_Float16)__expf(sc0 - M);
    pb[1] = (_Float16)__expf(sc1 - M);
    pb[2] = (_Float16)__expf(sc2 - M);
    pb[3] = (_Float16)__expf(sc3 - M);
    S += (float)pb[0] + (float)pb[1] + (float)pb[2] + (float)pb[3];
    const _Float16* hp0 = hTb + ((size_t)mt * 64 + col) * 64 + ml0;
#pragma unroll
    for (int ot = 0; ot < 4; ++ot) {
      h4 af = *(const h4*)(hp0 + (size_t)ot * 16 * 64);
      acc[ot] = __builtin_amdgcn_mfma_f32_16x16x16f16(af, pb, acc[ot], 0, 0, 0);
    }
  }

  // reduce S across the 4 groups (same row)
  S += __shfl_xor(S, 16, 64);
  S += __shfl_xor(S, 32, 64);

  __shared__ float red[8][16][64];
  __shared__ float Mw[8][16];
  __shared__ float Sw[8][16];
  if (l < 16) { Mw[w][l] = M; Sw[w][l] = S; }
#pragma unroll
  for (int ot = 0; ot < 4; ++ot)
    *(f4*)&red[w][col][ot * 16 + grp * 4] = acc[ot];
  __syncthreads();

  if (t < 256) {
    // combine 8 waves (different m-ranges, different running max)
    int nl = t >> 4, o0 = (t & 15) * 4;
    float Ms = Mw[0][nl];
#pragma unroll
    for (int ww = 1; ww < 8; ++ww) Ms = fmaxf(Ms, Mw[ww][nl]);
    float Ssum = 0.f;
    f4 v = {};
#pragma unroll
    for (int ww = 0; ww < 8; ++ww) {
      float f = __expf(Mw[ww][nl] - Ms);
      Ssum = fmaf(Sw[ww][nl], f, Ssum);
      f4 r = *(const f4*)&red[ww][nl][o0];
      v += r * f;
    }
    float is = 1.0f / Ssum;
    v *= is;
    if (last) {
      *(f4*)(hp + ((size_t)h * Nn + n0 + nl) * HID + o0) = v;
    } else {
      f4 xo;
#pragma unroll
      for (int k = 0; k < 4; ++k) xo[k] = v[k] > 0.f ? v[k] : expm1f(v[k]);
      *(f4*)(xn + (size_t)(n0 + nl) * FIN + h * HID + o0) = xo;
    }
  }
}

// ---------------- final output: mean over heads + elu ----------------
__global__ void k_out(const float* __restrict__ hp, float* __restrict__ out) {
  int idx = blockIdx.x * 256 + threadIdx.x;   // N*64
  int n = idx >> 6, o = idx & 63;
  size_t b = (size_t)n * HID + o;
  float v = 0.25f * (hp[b] + hp[(size_t)Nn * HID + b] +
                     hp[2 * (size_t)Nn * HID + b] + hp[3 * (size_t)Nn * HID + b]);
  out[idx] = v > 0.f ? v : expm1f(v);
}

extern "C" void kernel_launch(void* const* d_in, const int* in_sizes, int n_in,
                              void* d_out, int out_size, void* d_ws, size_t ws_size,
                              hipStream_t stream) {
  const float* x_in = (const float*)d_in[0];
  const int* adj = (const int*)d_in[1];
  const float* e = (const float*)d_in[2];
  const float* We = (const float*)d_in[3];
  const float* W = (const float*)d_in[4];
  const float* a = (const float*)d_in[5];
  float* out = (float*)d_out;

  char* ws = (char*)d_ws;
  size_t off = 0;
  auto alloc = [&](size_t bytes) -> void* {
    off = (off + 255) & ~(size_t)255;
    void* p = ws + off;
    off += bytes;
    return p;
  };
  float* coef = (float*)alloc((size_t)NL * NH * EFEAT * sizeof(float));
  float* s1 = (float*)alloc((size_t)NH * Nn * sizeof(float));
  float* s2 = (float*)alloc((size_t)NH * Nn * sizeof(float));
  float* hp = (float*)alloc((size_t)NH * Nn * HID * sizeof(float));
  float* xA = (float*)alloc((size_t)Nn * FIN * sizeof(float));
  float* xB = (float*)alloc((size_t)Nn * FIN * sizeof(float));
  _Float16* hT = (_Float16*)alloc((size_t)NH * 32 * 64 * 64 * sizeof(_Float16));
  _Float16* es = (_Float16*)alloc((size_t)NL * NH * 32 * Nn * 64 * sizeof(_Float16));

  hipLaunchKernelGGL(k_coef, dim3(NL * NH), dim3(256), 0, stream, W, We, a, coef);

  size_t total = (size_t)Nn * Nn;
  hipLaunchKernelGGL((k_escore<NL * NH>), dim3((unsigned)(total / 256)), dim3(256), 0, stream,
                     e, adj, coef, es);

  for (int l = 0; l < NL; ++l) {
    const float* xcur = (l == 0) ? x_in : ((l == 1) ? xA : xB);
    float* xn = (l == 0) ? xA : xB;
    hipLaunchKernelGGL(k_h, dim3(Nn / 8), dim3(256), 0, stream, xcur, W, a, l, hT, s1, s2);
    hipLaunchKernelGGL(k_attn, dim3(NH, Nn / 16), dim3(512), 0, stream,
                       es, hT, s1, s2, hp, xn, l, l == NL - 1 ? 1 : 0);
  }
  hipLaunchKernelGGL(k_out, dim3(Nn * HID / 256), dim3(256), 0, stream, hp, out);
}

// Round 5
// 259.642 us; speedup vs baseline: 1.1991x; 1.1991x over previous
//
#include <hip/hip_runtime.h>
#include <cstdint>
#include <cstddef>

#define Nn 2048
#define FIN 256
#define EFEAT 32
#define HID 64
#define NH 4
#define NL 3
#define LRELU_A 0.2f

typedef _Float16 h4 __attribute__((ext_vector_type(4)));
typedef _Float16 h8 __attribute__((ext_vector_type(8)));
typedef float f4 __attribute__((ext_vector_type(4)));

#define NEGH ((_Float16)(-60000.0f))

// ---------------- coef[l,h,f] = sum_i W_e[l,h,f,i] * (sum_o W[l,h,i,o]*a3[l,h,o]) ----------------
__global__ void k_coef(const float* __restrict__ W, const float* __restrict__ We,
                       const float* __restrict__ a, float* __restrict__ coef) {
  int lh = blockIdx.x;          // 0..11  (l*4+h)
  int t = threadIdx.x;          // 256
  __shared__ float tl[FIN];
  const float* Wb = W + (size_t)lh * FIN * HID;
  const float* ab = a + (size_t)lh * (3 * HID) + 2 * HID;
  float acc = 0.f;
#pragma unroll 8
  for (int o = 0; o < HID; ++o) acc = fmaf(Wb[(size_t)t * HID + o], ab[o], acc);
  tl[t] = acc;
  __syncthreads();
  if (t < EFEAT) {
    const float* Web = We + ((size_t)lh * EFEAT + t) * FIN;
    float c = 0.f;
    for (int i = 0; i < FIN; ++i) c = fmaf(Web[i], tl[i], c);
    coef[lh * EFEAT + t] = c;
  }
}

// ---------------- e-score precompute, fp16, m-tiled layout es[c][m/64][n][m%64] ----------------
template <int C>
__global__ __launch_bounds__(256) void k_escore(
    const float* __restrict__ e, const int* __restrict__ adj,
    const float* __restrict__ coef, _Float16* __restrict__ es) {
  size_t idx = (size_t)blockIdx.x * 256 + threadIdx.x;   // n*Nn + m
  int m = (int)(idx & (Nn - 1));
  int n = (int)(idx >> 11);
  int mt = m >> 6, ml = m & 63;
  const size_t cstride = (size_t)32 * Nn * 64;
  size_t sbase = ((size_t)mt * Nn + n) * 64 + (size_t)ml;
  int aj = adj[idx];
  float evv[EFEAT] = {};
  if (aj != 0) {
    const float4* ep = (const float4*)(e + idx * EFEAT);
#pragma unroll
    for (int g = 0; g < 8; ++g) {
      float4 v = ep[g];
      evv[g * 4 + 0] = v.x; evv[g * 4 + 1] = v.y; evv[g * 4 + 2] = v.z; evv[g * 4 + 3] = v.w;
    }
  }
#pragma clang loop unroll(disable)
  for (int c = 0; c < C; ++c) {
    const float* cf = coef + c * EFEAT;   // wave-uniform -> s_load
    float acc = 0.f;
#pragma unroll
    for (int f = 0; f < EFEAT; ++f) acc = fmaf(evv[f], cf[f], acc);
    es[(size_t)c * cstride + sbase] = aj ? (_Float16)acc : NEGH;
  }
}

// ---------------- h = x @ W[l]; emit hT fp16 m-tiled [h][n/64][o][n%64], s1, s2 ----------------
// j=4 rows/block -> 512 blocks (2 blocks/CU) for latency hiding.
__global__ __launch_bounds__(256) void k_h(
    const float* __restrict__ x, const float* __restrict__ W,
    const float* __restrict__ a, int layer,
    _Float16* __restrict__ hT, float* __restrict__ s1, float* __restrict__ s2) {
  int t = threadIdx.x;
  int n0 = blockIdx.x * 4;
  int h = t >> 6, o = t & 63;
  const float* Wb = W + ((size_t)(layer * NH + h) * FIN) * HID + o;
  const float* xb = x + (size_t)n0 * FIN;
  float acc[4] = {};
  for (int i0 = 0; i0 < FIN; i0 += 4) {
    float w0 = Wb[(size_t)(i0 + 0) * HID];
    float w1 = Wb[(size_t)(i0 + 1) * HID];
    float w2 = Wb[(size_t)(i0 + 2) * HID];
    float w3 = Wb[(size_t)(i0 + 3) * HID];
#pragma unroll
    for (int j = 0; j < 4; ++j) {
      float4 xv = *(const float4*)(xb + (size_t)j * FIN + i0);   // uniform -> SGPR
      acc[j] = fmaf(xv.x, w0, acc[j]);
      acc[j] = fmaf(xv.y, w1, acc[j]);
      acc[j] = fmaf(xv.z, w2, acc[j]);
      acc[j] = fmaf(xv.w, w3, acc[j]);
    }
  }
  const float* ab = a + (size_t)(layer * NH + h) * (3 * HID);
  float a1v = ab[o], a2v = ab[HID + o];
#pragma unroll
  for (int j = 0; j < 4; ++j) {
    float r1 = acc[j] * a1v, r2 = acc[j] * a2v;
#pragma unroll
    for (int d = 1; d < 64; d <<= 1) {
      r1 += __shfl_xor(r1, d, 64);
      r2 += __shfl_xor(r2, d, 64);
    }
    if (o == 0) { s1[h * Nn + n0 + j] = r1; s2[h * Nn + n0 + j] = r2; }
  }
  int mt = n0 >> 6, ml = n0 & 63;
  h4 hv;
#pragma unroll
  for (int j = 0; j < 4; ++j) hv[j] = (_Float16)acc[j];
  *(h4*)(hT + (((size_t)h * 32 + mt) * 64 + o) * 64 + ml) = hv;
}

// ---------------- attention: two-pass, h'^T = h^T @ p^T via mfma_f32_16x16x16f16 ----------------
// block = 8 waves (512 thr), one head, 16 rows. Wave w covers m in [w*256, w*256+256) -> 16 iters.
// Pass 1: scores -> fp16 regs, per-lane max, NO shuffles/branches in loop (pipelineable).
// Pass 2: M fixed -> exp+MFMA independent per iter, no rescale.
// Lane l: row n = n0 + (l&15); B-frag m-subchunk (l>>4)*4+j.
__global__ __launch_bounds__(512, 2) void k_attn(
    const _Float16* __restrict__ es, const _Float16* __restrict__ hT,
    const float* __restrict__ s1, const float* __restrict__ s2,
    float* __restrict__ hp, float* __restrict__ xn, int layer, int last) {
  int h = blockIdx.x;
  int n0 = blockIdx.y * 16;
  int t = threadIdx.x;
  int w = t >> 6;
  int l = t & 63;
  int col = l & 15, grp = l >> 4;
  int n = n0 + col;
  float s1v = s1[h * Nn + n];
  const _Float16* esb = es + (size_t)(layer * NH + h) * ((size_t)32 * Nn * 64);
  const _Float16* hTb = hT + (size_t)h * ((size_t)32 * 64 * 64);
  const float* s2b = s2 + h * Nn;

  // ---- pass 1: scores ----
  h4 sc16[16];
  float pmax = -3.0e38f;
#pragma unroll
  for (int c16 = 0; c16 < 16; ++c16) {
    int m0 = w * 256 + c16 * 16;
    int mt = m0 >> 6;
    int ml0 = (m0 & 63) + grp * 4;
    h4 ev = *(const h4*)(esb + ((size_t)mt * Nn + n) * 64 + ml0);
    float4 sv = *(const float4*)(s2b + m0 + grp * 4);
    float sc0 = s1v + sv.x + (float)ev[0]; sc0 = fmaxf(sc0, LRELU_A * sc0);
    float sc1 = s1v + sv.y + (float)ev[1]; sc1 = fmaxf(sc1, LRELU_A * sc1);
    float sc2 = s1v + sv.z + (float)ev[2]; sc2 = fmaxf(sc2, LRELU_A * sc2);
    float sc3 = s1v + sv.w + (float)ev[3]; sc3 = fmaxf(sc3, LRELU_A * sc3);
    h4 sch;
    sch[0] = (_Float16)sc0; sch[1] = (_Float16)sc1;
    sch[2] = (_Float16)sc2; sch[3] = (_Float16)sc3;
    sc16[c16] = sch;
    pmax = fmaxf(pmax, fmaxf(fmaxf(sc0, sc1), fmaxf(sc2, sc3)));
  }
  // per-row max across the 4 grp lane-groups (lanes l, l^16, l^32, l^48 share row n)
  pmax = fmaxf(pmax, __shfl_xor(pmax, 16, 64));
  float M = fmaxf(pmax, __shfl_xor(pmax, 32, 64));

  // ---- pass 2: exp + MFMA (no rescale, iterations independent) ----
  float S = 0.f;
  f4 acc[4] = {};
#pragma unroll
  for (int c16 = 0; c16 < 16; ++c16) {
    int m0 = w * 256 + c16 * 16;
    int mt = m0 >> 6;
    int ml0 = (m0 & 63) + grp * 4;
    h4 scv = sc16[c16];
    float p0 = __expf((float)scv[0] - M);
    float p1 = __expf((float)scv[1] - M);
    float p2 = __expf((float)scv[2] - M);
    float p3 = __expf((float)scv[3] - M);
    S += p0 + p1 + p2 + p3;
    h4 pb;
    pb[0] = (_Float16)p0; pb[1] = (_Float16)p1;
    pb[2] = (_Float16)p2; pb[3] = (_Float16)p3;
    const _Float16* hp0 = hTb + ((size_t)mt * 64 + col) * 64 + ml0;
#pragma unroll
    for (int ot = 0; ot < 4; ++ot) {
      h4 af = *(const h4*)(hp0 + (size_t)ot * 16 * 64);
      acc[ot] = __builtin_amdgcn_mfma_f32_16x16x16f16(af, pb, acc[ot], 0, 0, 0);
    }
  }
  S += __shfl_xor(S, 16, 64);
  S += __shfl_xor(S, 32, 64);

  __shared__ float red[8][16][64];
  __shared__ float Mw[8][16];
  __shared__ float Sw[8][16];
  if (l < 16) { Mw[w][l] = M; Sw[w][l] = S; }
#pragma unroll
  for (int ot = 0; ot < 4; ++ot)
    *(f4*)&red[w][col][ot * 16 + grp * 4] = acc[ot];
  __syncthreads();

  if (t < 256) {
    int nl = t >> 4, o0 = (t & 15) * 4;
    float Ms = Mw[0][nl];
#pragma unroll
    for (int ww = 1; ww < 8; ++ww) Ms = fmaxf(Ms, Mw[ww][nl]);
    float Ssum = 0.f;
    f4 v = {};
#pragma unroll
    for (int ww = 0; ww < 8; ++ww) {
      float f = __expf(Mw[ww][nl] - Ms);
      Ssum = fmaf(Sw[ww][nl], f, Ssum);
      f4 r = *(const f4*)&red[ww][nl][o0];
      v += r * f;
    }
    float is = 1.0f / Ssum;
    v *= is;
    if (last) {
      *(f4*)(hp + ((size_t)h * Nn + n0 + nl) * HID + o0) = v;
    } else {
      f4 xo;
#pragma unroll
      for (int k = 0; k < 4; ++k) xo[k] = v[k] > 0.f ? v[k] : expm1f(v[k]);
      *(f4*)(xn + (size_t)(n0 + nl) * FIN + h * HID + o0) = xo;
    }
  }
}

// ---------------- final output: mean over heads + elu ----------------
__global__ void k_out(const float* __restrict__ hp, float* __restrict__ out) {
  int idx = blockIdx.x * 256 + threadIdx.x;   // N*64
  int n = idx >> 6, o = idx & 63;
  size_t b = (size_t)n * HID + o;
  float v = 0.25f * (hp[b] + hp[(size_t)Nn * HID + b] +
                     hp[2 * (size_t)Nn * HID + b] + hp[3 * (size_t)Nn * HID + b]);
  out[idx] = v > 0.f ? v : expm1f(v);
}

extern "C" void kernel_launch(void* const* d_in, const int* in_sizes, int n_in,
                              void* d_out, int out_size, void* d_ws, size_t ws_size,
                              hipStream_t stream) {
  const float* x_in = (const float*)d_in[0];
  const int* adj = (const int*)d_in[1];
  const float* e = (const float*)d_in[2];
  const float* We = (const float*)d_in[3];
  const float* W = (const float*)d_in[4];
  const float* a = (const float*)d_in[5];
  float* out = (float*)d_out;

  char* ws = (char*)d_ws;
  size_t off = 0;
  auto alloc = [&](size_t bytes) -> void* {
    off = (off + 255) & ~(size_t)255;
    void* p = ws + off;
    off += bytes;
    return p;
  };
  float* coef = (float*)alloc((size_t)NL * NH * EFEAT * sizeof(float));
  float* s1 = (float*)alloc((size_t)NH * Nn * sizeof(float));
  float* s2 = (float*)alloc((size_t)NH * Nn * sizeof(float));
  float* hp = (float*)alloc((size_t)NH * Nn * HID * sizeof(float));
  float* xA = (float*)alloc((size_t)Nn * FIN * sizeof(float));
  float* xB = (float*)alloc((size_t)Nn * FIN * sizeof(float));
  _Float16* hT = (_Float16*)alloc((size_t)NH * 32 * 64 * 64 * sizeof(_Float16));
  _Float16* es = (_Float16*)alloc((size_t)NL * NH * 32 * Nn * 64 * sizeof(_Float16));

  hipLaunchKernelGGL(k_coef, dim3(NL * NH), dim3(256), 0, stream, W, We, a, coef);

  size_t total = (size_t)Nn * Nn;
  hipLaunchKernelGGL((k_escore<NL * NH>), dim3((unsigned)(total / 256)), dim3(256), 0, stream,
                     e, adj, coef, es);

  for (int l = 0; l < NL; ++l) {
    const float* xcur = (l == 0) ? x_in : ((l == 1) ? xA : xB);
    float* xn = (l == 0) ? xA : xB;
    hipLaunchKernelGGL(k_h, dim3(Nn / 4), dim3(256), 0, stream, xcur, W, a, l, hT, s1, s2);
    hipLaunchKernelGGL(k_attn, dim3(NH, Nn / 16), dim3(512), 0, stream,
                       es, hT, s1, s2, hp, xn, l, l == NL - 1 ? 1 : 0);
  }
  hipLaunchKernelGGL(k_out, dim3(Nn * HID / 256), dim3(256), 0, stream, hp, out);
}